// Round 17
// baseline (135.337 us; speedup 1.0000x reference)
//
#include <hip/hip_runtime.h>
#include <math.h>

#define N_NODES 100000
#define N_EDGES 1250000
#define IN_DIM 6
#define HID 64

#define BIN_SHIFT 8
#define BIN_NODES 256
#define NBIN 391                     // ceil(100000/256)
#define A_BLOCKS 500
#define EPB (N_EDGES / A_BLOCKS)     // 2500 exactly
#define CAP 4096                     // per-bin region capacity (max count ~3460)
#define SOFF (NBIN * CAP)            // src-chain region offset in rec

// bf16 <-> f32 helpers
__device__ inline float lo16(unsigned u) { return __uint_as_float(u << 16); }
__device__ inline float hi16(unsigned u) { return __uint_as_float(u & 0xffff0000u); }
__device__ inline unsigned short f2bf(float f) {
    unsigned u = __float_as_uint(f);
    u += 0x7FFFu + ((u >> 16) & 1u);
    return (unsigned short)(u >> 16);
}
__device__ inline unsigned pack2(float a, float b) {
    return (unsigned)f2bf(a) | ((unsigned)f2bf(b) << 16);
}

// --- binFill: two-pass block-local count + global region alloc + scatter ---
// recD (bin b at [b*CAP, b*CAP+cntD)) = (dstLow<<17)|src
// recS (bin b at [SOFF+b*CAP, ...))   = (srcLow<<17)|dst
__global__ __launch_bounds__(512) void binFill(const int* __restrict__ src,
                                               const int* __restrict__ dst,
                                               int* __restrict__ cnt,
                                               unsigned* __restrict__ rec) {
    __shared__ int lc[2 * NBIN];   // local counts, then local cursors
    __shared__ int lb[2 * NBIN];   // allocated base positions
    int t = threadIdx.x;
    for (int i = t; i < 2 * NBIN; i += 512) lc[i] = 0;
    __syncthreads();
    int base = blockIdx.x * EPB;
    for (int i0 = t * 4; i0 < EPB; i0 += 2048) {   // EPB % 4 == 0
        int4 d4 = *(const int4*)&dst[base + i0];
        int4 s4 = *(const int4*)&src[base + i0];
        atomicAdd(&lc[d4.x >> BIN_SHIFT], 1);
        atomicAdd(&lc[d4.y >> BIN_SHIFT], 1);
        atomicAdd(&lc[d4.z >> BIN_SHIFT], 1);
        atomicAdd(&lc[d4.w >> BIN_SHIFT], 1);
        atomicAdd(&lc[NBIN + (s4.x >> BIN_SHIFT)], 1);
        atomicAdd(&lc[NBIN + (s4.y >> BIN_SHIFT)], 1);
        atomicAdd(&lc[NBIN + (s4.z >> BIN_SHIFT)], 1);
        atomicAdd(&lc[NBIN + (s4.w >> BIN_SHIFT)], 1);
    }
    __syncthreads();
    for (int i = t; i < 2 * NBIN; i += 512) {
        int c = lc[i];
        int off = (c > 0) ? atomicAdd(&cnt[i], c) : 0;
        int bin = (i < NBIN) ? i : (i - NBIN);
        lb[i] = ((i < NBIN) ? bin * CAP : SOFF + bin * CAP) + off;
        lc[i] = 0;   // becomes local cursor
    }
    __syncthreads();
    for (int i0 = t * 4; i0 < EPB; i0 += 2048) {
        int4 d4 = *(const int4*)&dst[base + i0];
        int4 s4 = *(const int4*)&src[base + i0];
        int bD0 = d4.x >> BIN_SHIFT, bD1 = d4.y >> BIN_SHIFT;
        int bD2 = d4.z >> BIN_SHIFT, bD3 = d4.w >> BIN_SHIFT;
        int p0 = lb[bD0] + atomicAdd(&lc[bD0], 1);
        int p1 = lb[bD1] + atomicAdd(&lc[bD1], 1);
        int p2 = lb[bD2] + atomicAdd(&lc[bD2], 1);
        int p3 = lb[bD3] + atomicAdd(&lc[bD3], 1);
        rec[p0] = ((unsigned)(d4.x & (BIN_NODES - 1)) << 17) | (unsigned)s4.x;
        rec[p1] = ((unsigned)(d4.y & (BIN_NODES - 1)) << 17) | (unsigned)s4.y;
        rec[p2] = ((unsigned)(d4.z & (BIN_NODES - 1)) << 17) | (unsigned)s4.z;
        rec[p3] = ((unsigned)(d4.w & (BIN_NODES - 1)) << 17) | (unsigned)s4.w;
        int bS0 = NBIN + (s4.x >> BIN_SHIFT), bS1 = NBIN + (s4.y >> BIN_SHIFT);
        int bS2 = NBIN + (s4.z >> BIN_SHIFT), bS3 = NBIN + (s4.w >> BIN_SHIFT);
        int q0 = lb[bS0] + atomicAdd(&lc[bS0], 1);
        int q1 = lb[bS1] + atomicAdd(&lc[bS1], 1);
        int q2 = lb[bS2] + atomicAdd(&lc[bS2], 1);
        int q3 = lb[bS3] + atomicAdd(&lc[bS3], 1);
        rec[q0] = ((unsigned)(s4.x & (BIN_NODES - 1)) << 17) | (unsigned)d4.x;
        rec[q1] = ((unsigned)(s4.y & (BIN_NODES - 1)) << 17) | (unsigned)d4.y;
        rec[q2] = ((unsigned)(s4.z & (BIN_NODES - 1)) << 17) | (unsigned)d4.z;
        rec[q3] = ((unsigned)(s4.w & (BIN_NODES - 1)) << 17) | (unsigned)d4.w;
    }
}

// --- disXH: per dst-bin 4-way hist -> deg, dis, xpad -----------------------
__global__ __launch_bounds__(512) void disXH(const unsigned* __restrict__ rec,
                                             const int* __restrict__ cnt,
                                             const float* __restrict__ x,
                                             int* __restrict__ deg,
                                             float* __restrict__ dis,
                                             uint4* __restrict__ xpad) {
    __shared__ int histS[4][BIN_NODES];
    int t = threadIdx.x, g = t >> 7;   // 4 sub-hists, 128 threads each
    if (t < 4 * BIN_NODES) { ((int*)histS)[t] = 0; ((int*)histS)[t + 512] = 0; }
    __syncthreads();
    int bin = blockIdx.x;
    int beg = bin * CAP, end = beg + cnt[bin];
    for (int j = beg + t; j < end; j += 512) atomicAdd(&histS[g][rec[j] >> 17], 1);
    __syncthreads();
    if (t < BIN_NODES) {
        int n = (bin << BIN_SHIFT) + t;
        if (n < N_NODES) {
            int h = histS[0][t] + histS[1][t] + histS[2][t] + histS[3][t];
            deg[n] = h;
            float d = rsqrtf((float)h + 1.0f);
            dis[n] = d;
            float2 xa = *(const float2*)&x[n * IN_DIM + 0];
            float2 xb = *(const float2*)&x[n * IN_DIM + 2];
            float2 xc = *(const float2*)&x[n * IN_DIM + 4];
            uint4 u;
            u.x = pack2(xa.x * d, xa.y * d);
            u.y = pack2(xb.x * d, xb.y * d);
            u.z = pack2(xc.x * d, xc.y * d);
            u.w = 0;
            xpad[n] = u;
        }
    }
}

// --- aggW: fused per-bin pipeline + last-block final sigmoid ---------------
__global__ __launch_bounds__(512) void aggW(const unsigned* __restrict__ rec,
                                            const int* __restrict__ cnt,
                                            const int* __restrict__ deg,
                                            const float* __restrict__ dis,
                                            const uint4* __restrict__ xpad,
                                            const float* __restrict__ W1,
                                            const float* __restrict__ b1,
                                            const float* __restrict__ W2,
                                            const float* __restrict__ b2,
                                            const float* __restrict__ Wfc,
                                            const float* __restrict__ bfc,
                                            float* __restrict__ vsum,
                                            int* __restrict__ done,
                                            float* __restrict__ out) {
    __shared__ unsigned srcL[CAP];          // 16 KB sorted src ids
    __shared__ float wlS[4][BIN_NODES];     // 4 KB wsum sub-accumulators
    __shared__ int degL[BIN_NODES];
    __shared__ int startS[BIN_NODES];
    __shared__ int cur[BIN_NODES];
    __shared__ int sc[BIN_NODES];
    __shared__ float sAll[BIN_NODES][8];    // s6 sums + d + cw
    __shared__ float w1s[IN_DIM * HID];     // [k][c]
    __shared__ float b1s[HID];
    __shared__ float vpart[HID];
    __shared__ int isLast;
    int t = threadIdx.x, g = t >> 7;        // 4 sub-accs, 128 threads each
    int bin = blockIdx.x;

    if (t < 4 * BIN_NODES / 2) { ((float*)wlS)[t] = 0.f; ((float*)wlS)[t + 512] = 0.f; }
    if (t < IN_DIM * HID) w1s[t] = W1[t];
    if (t >= 512 - HID) { int c = t - (512 - HID); b1s[c] = b1[c]; vpart[c] = 0.f; }
    __syncthreads();

    // phase A: local wsum from src-chain
    {
        int beg = SOFF + bin * CAP, end = beg + cnt[NBIN + bin];
        for (int j = beg + t; j < end; j += 512) {
            unsigned r = rec[j];
            atomicAdd(&wlS[g][r >> 17], dis[r & 131071u]);
        }
    }
    __syncthreads();

    // phase B: deg -> scan -> offsets; d, cw
    if (t < BIN_NODES) {
        int n = (bin << BIN_SHIFT) + t;
        int h = (n < N_NODES) ? deg[n] : 0;
        degL[t] = h;
        sc[t] = h;
        float d = (n < N_NODES) ? rsqrtf((float)h + 1.0f) : 0.f;
        float wloc = wlS[0][t] + wlS[1][t] + wlS[2][t] + wlS[3][t];
        sAll[t][6] = d;
        sAll[t][7] = (n < N_NODES) ? d * (wloc + d) : 0.f;
    }
    __syncthreads();
    for (int off = 1; off < BIN_NODES; off <<= 1) {
        int add = 0;
        if (t < BIN_NODES && t >= off) add = sc[t - off];
        __syncthreads();
        if (t < BIN_NODES) sc[t] += add;
        __syncthreads();
    }
    if (t < BIN_NODES) {
        int st = sc[t] - degL[t];
        startS[t] = st;
        cur[t] = st;
    }
    __syncthreads();

    // phase C: counting-sort scatter (dst-chain)
    {
        int beg = bin * CAP, end = beg + cnt[bin];
        for (int j = beg + t; j < end; j += 512) {
            unsigned r = rec[j];
            int pos = atomicAdd(&cur[r >> 17], 1);
            if (pos < CAP) srcL[pos] = r & 131071u;
        }
    }
    __syncthreads();

    // phase D: 2 threads/node register accumulation
    {
        int node = t >> 1, sub = t & 1;
        int st = startS[node], cn = degL[node];
        int lim = min(st + cn, CAP);
        float s0 = 0.f, s1 = 0.f, s2 = 0.f, s3 = 0.f, s4 = 0.f, s5 = 0.f;
        for (int k = st + sub; k < lim; k += 2) {
            uint4 px = xpad[srcL[k]];
            s0 += lo16(px.x); s1 += hi16(px.x);
            s2 += lo16(px.y); s3 += hi16(px.y);
            s4 += lo16(px.z); s5 += hi16(px.z);
        }
        s0 += __shfl_xor(s0, 1, 64);
        s1 += __shfl_xor(s1, 1, 64);
        s2 += __shfl_xor(s2, 1, 64);
        s3 += __shfl_xor(s3, 1, 64);
        s4 += __shfl_xor(s4, 1, 64);
        s5 += __shfl_xor(s5, 1, 64);
        if (sub == 0) {
            int n = (bin << BIN_SHIFT) + node;
            if (n < N_NODES) {                  // self term
                uint4 px = xpad[n];
                s0 += lo16(px.x); s1 += hi16(px.x);
                s2 += lo16(px.y); s3 += hi16(px.y);
                s4 += lo16(px.z); s5 += hi16(px.z);
            }
            sAll[node][0] = s0; sAll[node][1] = s1; sAll[node][2] = s2;
            sAll[node][3] = s3; sAll[node][4] = s4; sAll[node][5] = s5;
        }
    }
    __syncthreads();

    // phase E: 8 groups x 64 lanes; each group 32 nodes; lane = channel
    {
        int c = t & 63, grp = t >> 6;
        float v = 0.f;
#pragma unroll
        for (int i = 0; i < 32; ++i) {
            int node = grp * 32 + i;
            float d = sAll[node][6], cw = sAll[node][7];
            float a = sAll[node][0] * w1s[0 * HID + c]
                    + sAll[node][1] * w1s[1 * HID + c]
                    + sAll[node][2] * w1s[2 * HID + c]
                    + sAll[node][3] * w1s[3 * HID + c]
                    + sAll[node][4] * w1s[4 * HID + c]
                    + sAll[node][5] * w1s[5 * HID + c];
            v += cw * fmaxf(d * a + b1s[c], 0.f);
        }
        atomicAdd(&vpart[c], v);
    }
    __syncthreads();
    if (t < HID) atomicAdd(&vsum[t], vpart[t]);

    // last-block final: g = b2 + (vsum/N)@W2 ; out = sigmoid(g@Wfc+bfc)
    if (t == 0) {
        __threadfence();
        int ticket = atomicAdd(done, 1);
        isLast = (ticket == NBIN - 1);
    }
    __syncthreads();
    if (isLast) {
        if (t < HID) vpart[t] = atomicAdd(&vsum[t], 0.f) * (1.0f / N_NODES);
        __syncthreads();
        if (t < HID) {
            float gg = b2[t];
            for (int k = 0; k < HID; ++k) gg += vpart[k] * W2[k * HID + t];
            float z = gg * Wfc[t];
            for (int off = 32; off > 0; off >>= 1) z += __shfl_down(z, off, 64);
            if (t == 0) out[0] = 1.0f / (1.0f + expf(-(z + bfc[0])));
        }
    }
}

extern "C" void kernel_launch(void* const* d_in, const int* in_sizes, int n_in,
                              void* d_out, int out_size, void* d_ws, size_t ws_size,
                              hipStream_t stream) {
    const float* x   = (const float*)d_in[0];
    const int*   ei  = (const int*)d_in[1];   // (2, E) row-major int32
    const float* W1  = (const float*)d_in[2];
    const float* b1  = (const float*)d_in[3];
    const float* W2  = (const float*)d_in[4];
    const float* b2  = (const float*)d_in[5];
    const float* Wfc = (const float*)d_in[6];
    const float* bfc = (const float*)d_in[7];
    const int* src = ei;
    const int* dst = ei + N_EDGES;

    char* ws = (char*)d_ws;
    size_t off = 0;
    auto alloc = (+[](char* base, size_t* o, size_t bytes) {
        char* p = base + *o;
        *o += (bytes + 255) & ~(size_t)255;
        return p;
    });
    int*      cnt  = (int*)     alloc(ws, &off, (size_t)2 * NBIN * 4);   // 3128 -> 3328
    float*    vsum = (float*)   alloc(ws, &off, 64 * 4);                 // 256 B
    int*      done = (int*)     alloc(ws, &off, 256);                    // ticket counter
    uint4*    xpad = (uint4*)   alloc(ws, &off, (size_t)N_NODES * 16);
    float*    dis  = (float*)   alloc(ws, &off, (size_t)N_NODES * 4);
    int*      deg  = (int*)     alloc(ws, &off, (size_t)N_NODES * 4);
    unsigned* rec  = (unsigned*)alloc(ws, &off, (size_t)2 * SOFF * 4);   // 12.8 MB

    // one memset covers cnt (3328) + vsum (256) + done (256)
    hipMemsetAsync(cnt, 0, 3840, stream);

    binFill<<<A_BLOCKS, 512, 0, stream>>>(src, dst, cnt, rec);
    disXH<<<NBIN, 512, 0, stream>>>(rec, cnt, x, deg, dis, xpad);
    aggW<<<NBIN, 512, 0, stream>>>(rec, cnt, deg, dis, xpad, W1, b1, W2, b2,
                                   Wfc, bfc, vsum, done, (float*)d_out);
}

// Round 18
// 125.061 us; speedup vs baseline: 1.0822x; 1.0822x over previous
//
#include <hip/hip_runtime.h>
#include <math.h>

#define N_NODES 100000
#define N_EDGES 1250000
#define IN_DIM 6
#define HID 64

#define BIN_SHIFT 8
#define BIN_NODES 256
#define NBIN 391                     // ceil(100000/256)
#define A_BLOCKS 250
#define EPB (N_EDGES / A_BLOCKS)     // 5000 exactly
#define CAP 4096                     // per-bin region capacity (max count ~3460)
#define SOFF (NBIN * CAP)            // src-chain region offset in rec

// bf16 <-> f32 helpers
__device__ inline float lo16(unsigned u) { return __uint_as_float(u << 16); }
__device__ inline float hi16(unsigned u) { return __uint_as_float(u & 0xffff0000u); }
__device__ inline unsigned short f2bf(float f) {
    unsigned u = __float_as_uint(f);
    u += 0x7FFFu + ((u >> 16) & 1u);
    return (unsigned short)(u >> 16);
}
__device__ inline unsigned pack2(float a, float b) {
    return (unsigned)f2bf(a) | ((unsigned)f2bf(b) << 16);
}

// --- binFill: two-pass block-local count + global region alloc + scatter ---
// recD (bin b at [b*CAP, b*CAP+cntD)) = (dstLow<<17)|src
// recS (bin b at [SOFF+b*CAP, ...))   = (srcLow<<17)|dst
__global__ __launch_bounds__(1024) void binFill(const int* __restrict__ src,
                                                const int* __restrict__ dst,
                                                int* __restrict__ cnt,
                                                unsigned* __restrict__ rec) {
    __shared__ int lc[2 * NBIN];   // local counts, then local cursors
    __shared__ int lb[2 * NBIN];   // allocated base positions
    int t = threadIdx.x;
    for (int i = t; i < 2 * NBIN; i += 1024) lc[i] = 0;
    __syncthreads();
    int base = blockIdx.x * EPB;
    // pass 1: local histogram (4 edges/thread/iter)
    for (int i0 = t * 4; i0 < EPB; i0 += 4096) {   // EPB % 4 == 0
        int4 d4 = *(const int4*)&dst[base + i0];
        int4 s4 = *(const int4*)&src[base + i0];
        atomicAdd(&lc[d4.x >> BIN_SHIFT], 1);
        atomicAdd(&lc[d4.y >> BIN_SHIFT], 1);
        atomicAdd(&lc[d4.z >> BIN_SHIFT], 1);
        atomicAdd(&lc[d4.w >> BIN_SHIFT], 1);
        atomicAdd(&lc[NBIN + (s4.x >> BIN_SHIFT)], 1);
        atomicAdd(&lc[NBIN + (s4.y >> BIN_SHIFT)], 1);
        atomicAdd(&lc[NBIN + (s4.z >> BIN_SHIFT)], 1);
        atomicAdd(&lc[NBIN + (s4.w >> BIN_SHIFT)], 1);
    }
    __syncthreads();
    // allocate block-private sub-segments via global atomics (1 per bin)
    for (int i = t; i < 2 * NBIN; i += 1024) {
        int c = lc[i];
        int off = (c > 0) ? atomicAdd(&cnt[i], c) : 0;
        int bin = (i < NBIN) ? i : (i - NBIN);
        int region = (i < NBIN) ? bin * CAP : SOFF + bin * CAP;
        lb[i] = region + off;
        lc[i] = 0;   // becomes local cursor
    }
    __syncthreads();
    // pass 2: scatter into allocated segments
    for (int i0 = t * 4; i0 < EPB; i0 += 4096) {
        int4 d4 = *(const int4*)&dst[base + i0];
        int4 s4 = *(const int4*)&src[base + i0];
        int bD0 = d4.x >> BIN_SHIFT, bD1 = d4.y >> BIN_SHIFT;
        int bD2 = d4.z >> BIN_SHIFT, bD3 = d4.w >> BIN_SHIFT;
        int p0 = lb[bD0] + atomicAdd(&lc[bD0], 1);
        int p1 = lb[bD1] + atomicAdd(&lc[bD1], 1);
        int p2 = lb[bD2] + atomicAdd(&lc[bD2], 1);
        int p3 = lb[bD3] + atomicAdd(&lc[bD3], 1);
        rec[p0] = ((unsigned)(d4.x & (BIN_NODES - 1)) << 17) | (unsigned)s4.x;
        rec[p1] = ((unsigned)(d4.y & (BIN_NODES - 1)) << 17) | (unsigned)s4.y;
        rec[p2] = ((unsigned)(d4.z & (BIN_NODES - 1)) << 17) | (unsigned)s4.z;
        rec[p3] = ((unsigned)(d4.w & (BIN_NODES - 1)) << 17) | (unsigned)s4.w;
        int bS0 = NBIN + (s4.x >> BIN_SHIFT), bS1 = NBIN + (s4.y >> BIN_SHIFT);
        int bS2 = NBIN + (s4.z >> BIN_SHIFT), bS3 = NBIN + (s4.w >> BIN_SHIFT);
        int q0 = lb[bS0] + atomicAdd(&lc[bS0], 1);
        int q1 = lb[bS1] + atomicAdd(&lc[bS1], 1);
        int q2 = lb[bS2] + atomicAdd(&lc[bS2], 1);
        int q3 = lb[bS3] + atomicAdd(&lc[bS3], 1);
        rec[q0] = ((unsigned)(s4.x & (BIN_NODES - 1)) << 17) | (unsigned)d4.x;
        rec[q1] = ((unsigned)(s4.y & (BIN_NODES - 1)) << 17) | (unsigned)d4.y;
        rec[q2] = ((unsigned)(s4.z & (BIN_NODES - 1)) << 17) | (unsigned)d4.z;
        rec[q3] = ((unsigned)(s4.w & (BIN_NODES - 1)) << 17) | (unsigned)d4.w;
    }
}

// --- disXH: per dst-bin 4-way hist -> deg, dis, xpad -----------------------
__global__ __launch_bounds__(1024) void disXH(const unsigned* __restrict__ rec,
                                              const int* __restrict__ cnt,
                                              const float* __restrict__ x,
                                              int* __restrict__ deg,
                                              float* __restrict__ dis,
                                              uint4* __restrict__ xpad) {
    __shared__ int histS[4][BIN_NODES];
    int t = threadIdx.x, g = t >> 8;
    if (t < 4 * BIN_NODES) ((int*)histS)[t] = 0;
    __syncthreads();
    int bin = blockIdx.x;
    int beg = bin * CAP, end = beg + cnt[bin];
    for (int j = beg + t; j < end; j += 1024) atomicAdd(&histS[g][rec[j] >> 17], 1);
    __syncthreads();
    if (t < BIN_NODES) {
        int n = (bin << BIN_SHIFT) + t;
        if (n < N_NODES) {
            int h = histS[0][t] + histS[1][t] + histS[2][t] + histS[3][t];
            deg[n] = h;
            float d = rsqrtf((float)h + 1.0f);
            dis[n] = d;
            float2 xa = *(const float2*)&x[n * IN_DIM + 0];
            float2 xb = *(const float2*)&x[n * IN_DIM + 2];
            float2 xc = *(const float2*)&x[n * IN_DIM + 4];
            uint4 u;
            u.x = pack2(xa.x * d, xa.y * d);
            u.y = pack2(xb.x * d, xb.y * d);
            u.z = pack2(xc.x * d, xc.y * d);
            u.w = 0;
            xpad[n] = u;
        }
    }
}

// --- aggW: fused per-bin pipeline ------------------------------------------
__global__ __launch_bounds__(1024) void aggW(const unsigned* __restrict__ rec,
                                             const int* __restrict__ cnt,
                                             const int* __restrict__ deg,
                                             const float* __restrict__ dis,
                                             const uint4* __restrict__ xpad,
                                             const float* __restrict__ W1,
                                             const float* __restrict__ b1,
                                             float* __restrict__ vsum) {
    __shared__ unsigned srcL[CAP];          // 16 KB sorted src ids
    __shared__ float wlS[4][BIN_NODES];     // 4 KB wsum sub-accumulators
    __shared__ int degL[BIN_NODES];
    __shared__ int startS[BIN_NODES];
    __shared__ int cur[BIN_NODES];
    __shared__ int sc[BIN_NODES];
    __shared__ float sAll[BIN_NODES][8];    // s6 sums + d + cw
    __shared__ float w1s[IN_DIM * HID];     // [k][c]
    __shared__ float b1s[HID];
    __shared__ float vpart[HID];
    int t = threadIdx.x, g = t >> 8;
    int bin = blockIdx.x;

    if (t < 4 * BIN_NODES) ((float*)wlS)[t] = 0.f;
    if (t < IN_DIM * HID) w1s[t] = W1[t];
    if (t >= 1024 - HID) { int c = t - (1024 - HID); b1s[c] = b1[c]; vpart[c] = 0.f; }
    __syncthreads();

    // phase A: local wsum from src-chain
    {
        int beg = SOFF + bin * CAP, end = beg + cnt[NBIN + bin];
        for (int j = beg + t; j < end; j += 1024) {
            unsigned r = rec[j];
            atomicAdd(&wlS[g][r >> 17], dis[r & 131071u]);
        }
    }
    __syncthreads();

    // phase B: deg -> scan -> offsets; d, cw
    if (t < BIN_NODES) {
        int n = (bin << BIN_SHIFT) + t;
        int h = (n < N_NODES) ? deg[n] : 0;
        degL[t] = h;
        sc[t] = h;
        float d = (n < N_NODES) ? rsqrtf((float)h + 1.0f) : 0.f;
        float wloc = wlS[0][t] + wlS[1][t] + wlS[2][t] + wlS[3][t];
        sAll[t][6] = d;
        sAll[t][7] = (n < N_NODES) ? d * (wloc + d) : 0.f;
    }
    __syncthreads();
    for (int off = 1; off < BIN_NODES; off <<= 1) {
        int add = 0;
        if (t < BIN_NODES && t >= off) add = sc[t - off];
        __syncthreads();
        if (t < BIN_NODES) sc[t] += add;
        __syncthreads();
    }
    if (t < BIN_NODES) {
        int st = sc[t] - degL[t];
        startS[t] = st;
        cur[t] = st;
    }
    __syncthreads();

    // phase C: counting-sort scatter (dst-chain)
    {
        int beg = bin * CAP, end = beg + cnt[bin];
        for (int j = beg + t; j < end; j += 1024) {
            unsigned r = rec[j];
            int pos = atomicAdd(&cur[r >> 17], 1);
            if (pos < CAP) srcL[pos] = r & 131071u;
        }
    }
    __syncthreads();

    // phase D: 4 threads/node register accumulation
    {
        int node = t >> 2, sub = t & 3;
        int st = startS[node], cn = degL[node];
        int lim = min(st + cn, CAP);
        float s0 = 0.f, s1 = 0.f, s2 = 0.f, s3 = 0.f, s4 = 0.f, s5 = 0.f;
        for (int k = st + sub; k < lim; k += 4) {
            uint4 px = xpad[srcL[k]];
            s0 += lo16(px.x); s1 += hi16(px.x);
            s2 += lo16(px.y); s3 += hi16(px.y);
            s4 += lo16(px.z); s5 += hi16(px.z);
        }
        s0 += __shfl_xor(s0, 1, 64); s0 += __shfl_xor(s0, 2, 64);
        s1 += __shfl_xor(s1, 1, 64); s1 += __shfl_xor(s1, 2, 64);
        s2 += __shfl_xor(s2, 1, 64); s2 += __shfl_xor(s2, 2, 64);
        s3 += __shfl_xor(s3, 1, 64); s3 += __shfl_xor(s3, 2, 64);
        s4 += __shfl_xor(s4, 1, 64); s4 += __shfl_xor(s4, 2, 64);
        s5 += __shfl_xor(s5, 1, 64); s5 += __shfl_xor(s5, 2, 64);
        if (sub == 0) {
            int n = (bin << BIN_SHIFT) + node;
            if (n < N_NODES) {                  // self term
                uint4 px = xpad[n];
                s0 += lo16(px.x); s1 += hi16(px.x);
                s2 += lo16(px.y); s3 += hi16(px.y);
                s4 += lo16(px.z); s5 += hi16(px.z);
            }
            sAll[node][0] = s0; sAll[node][1] = s1; sAll[node][2] = s2;
            sAll[node][3] = s3; sAll[node][4] = s4; sAll[node][5] = s5;
        }
    }
    __syncthreads();

    // phase E: 16 groups x 64 lanes; lane = channel, sAll broadcast reads
    {
        int c = t & 63, grp = t >> 6;
        float v = 0.f;
#pragma unroll
        for (int i = 0; i < 16; ++i) {
            int node = grp * 16 + i;
            float d = sAll[node][6], cw = sAll[node][7];
            float a = sAll[node][0] * w1s[0 * HID + c]
                    + sAll[node][1] * w1s[1 * HID + c]
                    + sAll[node][2] * w1s[2 * HID + c]
                    + sAll[node][3] * w1s[3 * HID + c]
                    + sAll[node][4] * w1s[4 * HID + c]
                    + sAll[node][5] * w1s[5 * HID + c];
            v += cw * fmaxf(d * a + b1s[c], 0.f);
        }
        atomicAdd(&vpart[c], v);
    }
    __syncthreads();
    if (t < HID) atomicAdd(&vsum[t], vpart[t]);
}

// --- final: g = b2 + (vsum/N) @ W2 ; out = sigmoid(g @ Wfc + bfc) ----------
__global__ void finalK(const float* __restrict__ vsum, const float* __restrict__ W2,
                       const float* __restrict__ b2, const float* __restrict__ Wfc,
                       const float* __restrict__ bfc, float* __restrict__ out) {
    __shared__ float vL[HID];
    int t = threadIdx.x;
    vL[t] = vsum[t] * (1.0f / N_NODES);
    __syncthreads();
    float g = b2[t];
    for (int k = 0; k < HID; ++k) g += vL[k] * W2[k * HID + t];
    float z = g * Wfc[t];
    for (int off = 32; off > 0; off >>= 1) z += __shfl_down(z, off, 64);
    if (t == 0) out[0] = 1.0f / (1.0f + expf(-(z + bfc[0])));
}

extern "C" void kernel_launch(void* const* d_in, const int* in_sizes, int n_in,
                              void* d_out, int out_size, void* d_ws, size_t ws_size,
                              hipStream_t stream) {
    const float* x   = (const float*)d_in[0];
    const int*   ei  = (const int*)d_in[1];   // (2, E) row-major int32
    const float* W1  = (const float*)d_in[2];
    const float* b1  = (const float*)d_in[3];
    const float* W2  = (const float*)d_in[4];
    const float* b2  = (const float*)d_in[5];
    const float* Wfc = (const float*)d_in[6];
    const float* bfc = (const float*)d_in[7];
    const int* src = ei;
    const int* dst = ei + N_EDGES;

    char* ws = (char*)d_ws;
    size_t off = 0;
    auto alloc = (+[](char* base, size_t* o, size_t bytes) {
        char* p = base + *o;
        *o += (bytes + 255) & ~(size_t)255;
        return p;
    });
    int*      cnt  = (int*)     alloc(ws, &off, (size_t)2 * NBIN * 4);   // 3128 B -> 3328
    float*    vsum = (float*)   alloc(ws, &off, 64 * 4);                 // adjacent to cnt
    uint4*    xpad = (uint4*)   alloc(ws, &off, (size_t)N_NODES * 16);
    float*    dis  = (float*)   alloc(ws, &off, (size_t)N_NODES * 4);
    int*      deg  = (int*)     alloc(ws, &off, (size_t)N_NODES * 4);
    unsigned* rec  = (unsigned*)alloc(ws, &off, (size_t)2 * SOFF * 4);   // 12.8 MB

    // one memset covers cnt (padded) + vsum
    hipMemsetAsync(cnt, 0, ((size_t)2 * NBIN * 4 + 255 & ~(size_t)255) + 64 * 4, stream);

    binFill<<<A_BLOCKS, 1024, 0, stream>>>(src, dst, cnt, rec);
    disXH<<<NBIN, 1024, 0, stream>>>(rec, cnt, x, deg, dis, xpad);
    aggW<<<NBIN, 1024, 0, stream>>>(rec, cnt, deg, dis, xpad, W1, b1, vsum);
    finalK<<<1, 64, 0, stream>>>(vsum, W2, b2, Wfc, bfc, (float*)d_out);
}